// Round 1
// baseline (254.666 us; speedup 1.0000x reference)
//
#include <hip/hip_runtime.h>

// DualModel3 R6: occupancy + pipeline depth. R5 counters: MfmaUtil 7.6%,
// VALUBusy 7.0%, HBM 11.6%, Occupancy 17% => latency-bound and GRID-starved
// (544 blocks x 256 thr = 2.125 blk/CU = 2.1 waves/SIMD; VGPR/LDS allow 3x
// more). R6 keeps the verified tiling math (BM=128 BN=64 BK=64, bf16-in-LDS,
// XOR-swizzled 128B rows, 32x32x16 MFMA, C/D col=lane&31,
// row=(r&3)+8*(r>>2)+4*(lane>>5)) and changes the execution shape:
//  - 512-thr blocks (8 waves, 4m x 2n wave grid of 32x32 tiles): same grid,
//    same per-block traffic, 2x waves/CU (17 waves/CU vs 8.5).
//  - LDS double-buffer (2 x 24KB): ONE barrier per K-step instead of two.
//  - manual barrier = s_waitcnt lgkmcnt(0) + raw s_barrier (8-phase-template
//    idiom): global prefetch loads stay in flight across the barrier
//    (__syncthreads would vmcnt(0)-drain them every iteration).
// Pipeline invariant at iter kt: LDS buf[kt&1] holds tile kt, regs hold tile
// kt+1; body = MFMA(buf p) | STAGE(p^1) | LOAD(kt+2) | barrier.

typedef __bf16 bf16_t;
typedef __bf16 bf16x4 __attribute__((ext_vector_type(4)));
typedef __bf16 bf16x8 __attribute__((ext_vector_type(8)));
typedef float  f32x4  __attribute__((ext_vector_type(4)));
typedef float  f32x16 __attribute__((ext_vector_type(16)));

__global__ __launch_bounds__(512, 6)   // cap VGPR<=85 -> 3 blocks/CU possible (LDS 48KB*3=144<=160)
void fused_dual(const float* __restrict__ x,    // [256,2048]
                const float* __restrict__ fcW,  // [1000,2048]
                const float* __restrict__ fcb,  // [1000]
                const float* __restrict__ W1,   // [4096,2048,4]
                const float* __restrict__ b1,   // [4096,4]
                const float* __restrict__ W2,   // [4096,4]
                const float* __restrict__ b2,   // [4096]
                float* __restrict__ out)        // x1[256*1000] ++ x2[256*4096]
{
    __shared__ __align__(16) char lds[2][24576];   // [buf][A 16KB | B 8KB]

    const int tid  = threadIdx.x;
    const int lane = tid & 63, w = tid >> 6;       // 8 waves
    const int l31  = lane & 31, half = lane >> 5;

    // XCD swizzle: 544 % 8 == 0 -> bijective; row-siblings adjacent (L2 reuse).
    const int idx = blockIdx.x;
    const int wid = (idx & 7) * 68 + (idx >> 3);
    const int cg  = wid >> 1, rg = wid & 1, m0 = rg * 128;
    const bool is_fc = (cg < 16);
    const int c0  = (is_fc ? cg : cg - 16) * 64;

    // ---- prefetch addressing (512 thr) ----
    // A: 128 rows x 64 k fp32 = 16 floats/thr
    const int arow = tid >> 2, aq = tid & 3;            // row 0..127, k-quarter
    const float* aBase = x + (m0 + arow) * 2048 + aq * 4;

    // B(fc): 64 rows x 64 k = 8 floats/thr. B(dec): 2 o's/wave, 1 f32x4/lane/o.
    const int brow = tid >> 3, bq = tid & 7;
    const float* bBase;
    if (is_fc) {
        int rowc = c0 + brow; if (rowc > 999) rowc = 999;   // stores guarded
        bBase = fcW + rowc * 2048 + bq * 8;
    } else {
        bBase = W1 + ((c0 >> 2) + w * 2) * 8192 + lane * 4; // o-major, +q*8192
    }

    f32x4 aR[4], bR[2];

    auto LOAD = [&](int kt) {
        const float* ap = aBase + kt * 64;
        #pragma unroll
        for (int j = 0; j < 4; ++j) aR[j] = *(const f32x4*)(ap + j * 16);
        if (is_fc) {
            const float* bp = bBase + kt * 64;
            bR[0] = *(const f32x4*)(bp);
            bR[1] = *(const f32x4*)(bp + 4);
        } else {
            const float* bp = bBase + kt * 256;      // 1KB contiguous per o
            bR[0] = *(const f32x4*)(bp);
            bR[1] = *(const f32x4*)(bp + 8192);
        }
    };

    auto STAGE = [&](int p) {
        char* lA = lds[p];
        char* lB = lds[p] + 16384;
        #pragma unroll
        for (int j = 0; j < 4; ++j) {
            const int kb = aq * 8 + j * 32;                  // byte off (=k*2)
            const int ad = arow * 128 + (((kb >> 4) ^ (arow & 7)) << 4) + (kb & 15);
            bf16x4 v;
            #pragma unroll
            for (int c = 0; c < 4; ++c) v[c] = (bf16_t)aR[j][c];
            *(bf16x4*)(lA + ad) = v;
        }
        if (is_fc) {
            const int ad = brow * 128 + ((bq ^ (brow & 7)) << 4);
            bf16x8 v;
            #pragma unroll
            for (int c = 0; c < 4; ++c) { v[c] = (bf16_t)bR[0][c]; v[4 + c] = (bf16_t)bR[1][c]; }
            *(bf16x8*)(lB + ad) = v;
        } else {
            // lane holds W1[o][k=lane][h0..3]; scatter h to rows n=(o_loc)*4+h
            const int gsub = ((lane >> 3) << 4) + (lane & 7) * 2; // pre-XOR
            #pragma unroll
            for (int q = 0; q < 2; ++q)
            #pragma unroll
            for (int h = 0; h < 4; ++h) {
                const int n = w * 8 + q * 4 + h;
                const int ad = n * 128 + (gsub ^ ((n & 7) << 4));
                *(bf16_t*)(lB + ad) = (bf16_t)bR[q][h];
            }
        }
    };

    const int mh = (w & 3) * 32, nh = (w >> 2) * 32;   // wave tile 32m x 32n
    f32x16 acc;
    #pragma unroll
    for (int r = 0; r < 16; ++r) acc[r] = 0.f;

    LOAD(0);
    STAGE(0);
    LOAD(1);
    asm volatile("s_waitcnt lgkmcnt(0)" ::: "memory");
    __builtin_amdgcn_s_barrier();
    asm volatile("" ::: "memory");

    const int mrow = mh + l31, nrow = nh + l31;
    #pragma unroll 2
    for (int kt = 0; kt < 32; ++kt) {
        const int p = kt & 1;
        const char* lA = lds[p];
        const char* lB = lds[p] + 16384;
        #pragma unroll
        for (int ks = 0; ks < 4; ++ks) {
            const int g = ks * 2 + half;
            bf16x8 bf = *(const bf16x8*)(lB + nrow * 128 + ((g ^ (nrow & 7)) << 4));
            bf16x8 af = *(const bf16x8*)(lA + mrow * 128 + ((g ^ (mrow & 7)) << 4));
            acc = __builtin_amdgcn_mfma_f32_32x32x16_bf16(af, bf, acc, 0, 0, 0);
        }
        if (kt < 31) STAGE(p ^ 1);        // vmcnt-waits on tile kt+1 regs
        if (kt < 30) LOAD(kt + 2);        // in flight across the barrier
        asm volatile("s_waitcnt lgkmcnt(0)" ::: "memory");
        __builtin_amdgcn_s_barrier();
        asm volatile("" ::: "memory");
    }

    // ---- epilogue ----  C/D: col=lane&31, row=(r&3)+8*(r>>2)+4*half
    if (is_fc) {
        const int c = c0 + nh + l31;
        if (c < 1000) {
            const float bias = fcb[c];
            #pragma unroll
            for (int r = 0; r < 16; ++r) {
                const int m = m0 + mh + (r & 3) + 8 * (r >> 2) + 4 * half;
                out[m * 1000 + c] = acc[r] + bias;
            }
        }
    } else {
        float* x2 = out + 256 * 1000;
        const int d = cg - 16;                    // decoder col-panel
        const int n_glob = c0 + nh + l31;
        const float b1v = b1[n_glob], w2v = W2[n_glob];
        const float b2v = b2[n_glob >> 2];
        // all frag reads fenced by the loop's final lgkmcnt+barrier -> reuse lds
        float* xs = (float*)lds;                  // [128 rows][16 o] fp32 = 8KB
        const int o_loc = (nh + l31) >> 2;
        #pragma unroll
        for (int r = 0; r < 16; ++r) {
            float h = acc[r] + b1v;
            h = (h >= 0.f) ? h : 0.1f * h;        // leaky relu
            float wv = h * w2v;
            wv += __shfl_xor(wv, 1, 64);          // decoder's 4 h-cols
            wv += __shfl_xor(wv, 2, 64);
            if ((lane & 3) == 0) {
                const int row = mh + (r & 3) + 8 * (r >> 2) + 4 * half;
                xs[row * 16 + o_loc] = wv + b2v;
            }
        }
        asm volatile("s_waitcnt lgkmcnt(0)" ::: "memory");
        __builtin_amdgcn_s_barrier();
        asm volatile("" ::: "memory");
        const int row = tid >> 2, part = tid & 3;
        f32x4 v = *(const f32x4*)(xs + row * 16 + part * 4);
        *(f32x4*)(x2 + (m0 + row) * 4096 + d * 16 + part * 4) = v;
    }
}

extern "C" void kernel_launch(void* const* d_in, const int* in_sizes, int n_in,
                              void* d_out, int out_size, void* d_ws, size_t ws_size,
                              hipStream_t stream)
{
    (void)in_sizes; (void)n_in; (void)d_ws; (void)ws_size; (void)out_size;
    const float* x   = (const float*)d_in[0];
    const float* fcW = (const float*)d_in[1];
    const float* fcb = (const float*)d_in[2];
    const float* W1  = (const float*)d_in[3];
    const float* b1  = (const float*)d_in[4];
    const float* W2  = (const float*)d_in[5];
    const float* b2  = (const float*)d_in[6];
    fused_dual<<<544, 512, 0, stream>>>(x, fcW, fcb, W1, b1, W2, b2, (float*)d_out);
}